// Round 1
// baseline (132964.197 us; speedup 1.0000x reference)
//
#include <hip/hip_runtime.h>

#define B_ 32
#define T_FULL 4096
#define EMB_ 256
#define XD_ 768
#define H_ 896
#define G3_ 2688
#define O_ 512
#define NWG_SCAN 56

typedef __attribute__((ext_vector_type(8))) short bf16x8;
typedef __attribute__((ext_vector_type(4))) float f32x4;

__device__ __forceinline__ f32x4 mfma16(bf16x8 a, bf16x8 b, f32x4 c) {
  return __builtin_amdgcn_mfma_f32_16x16x32_bf16(a, b, c, 0, 0, 0);
}

__device__ __forceinline__ unsigned short f2bf(float x) {
  union { float f; unsigned u; } v; v.f = x;
  unsigned r = v.u + 0x7fffu + ((v.u >> 16) & 1u);
  return (unsigned short)(r >> 16);
}
__device__ __forceinline__ float bf2f(unsigned short h) {
  union { float f; unsigned u; } v; v.u = ((unsigned)h) << 16;
  return v.f;
}

__global__ __launch_bounds__(256) void cvt_bf16(const float* __restrict__ in,
                                                unsigned short* __restrict__ out, int n) {
  for (int i = blockIdx.x * 256 + threadIdx.x; i < n; i += gridDim.x * 256)
    out[i] = f2bf(in[i]);
}

// VAR: 0 = gates (A = concat(emb[sample], icnd) built on the fly, out fp32 [row][2688])
//      1 = fc1   (A = ornn bf16, out bf16 relu [row][896])
//      2 = fc2   (A = hidden bf16, out fp32 scattered to d_out [b][t][512])
template<int VAR>
__global__ __launch_bounds__(256) void gemm_bf16(
    const unsigned short* __restrict__ A,
    const int* __restrict__ sample,
    const float* __restrict__ icnd,
    const unsigned short* __restrict__ embb,
    const unsigned short* __restrict__ W,
    const float* __restrict__ bias,
    float* __restrict__ outf,
    unsigned short* __restrict__ outb,
    int t0) {
  constexpr int K = (VAR == 0) ? XD_ : H_;
  constexpr int N = (VAR == 0) ? G3_ : (VAR == 1 ? H_ : O_);
  constexpr int LDT = 48;
  __shared__ __align__(16) unsigned short Asl[128 * LDT];
  __shared__ __align__(16) unsigned short Bsl[128 * LDT];
  const int tid = threadIdx.x;
  const int rowBase = blockIdx.y * 128, colBase = blockIdx.x * 128;
  const int lane = tid & 63, wid = tid >> 6;
  const int wm = wid >> 1, wn = wid & 1;
  const int lr = lane & 15, lk = lane >> 4;
  const f32x4 fzero = {0.f, 0.f, 0.f, 0.f};
  f32x4 acc[4][4];
#pragma unroll
  for (int i = 0; i < 4; ++i)
#pragma unroll
    for (int j = 0; j < 4; ++j) acc[i][j] = fzero;

  for (int k0 = 0; k0 < K; k0 += 32) {
#pragma unroll
    for (int s = 0; s < 2; ++s) {
      const int seg = tid + s * 256;           // 512 segments of 8 elems
      const int r = seg >> 2, kg = (seg & 3) * 8;
      const int kk = k0 + kg;
      bf16x8 va;
      if (VAR == 0) {
        const int rowG = rowBase + r;
        const int b = rowG & 31, t = t0 + (rowG >> 5);
        if (kk < EMB_) {
          const int e = sample[b * T_FULL + t];
          va = *(const bf16x8*)(embb + e * EMB_ + kk);
        } else {
          const float* p = icnd + ((size_t)(b * T_FULL + t)) * 512 + (kk - EMB_);
          const float4 f0 = *(const float4*)p;
          const float4 f1 = *(const float4*)(p + 4);
          va[0] = (short)f2bf(f0.x); va[1] = (short)f2bf(f0.y);
          va[2] = (short)f2bf(f0.z); va[3] = (short)f2bf(f0.w);
          va[4] = (short)f2bf(f1.x); va[5] = (short)f2bf(f1.y);
          va[6] = (short)f2bf(f1.z); va[7] = (short)f2bf(f1.w);
        }
      } else {
        va = *(const bf16x8*)(A + (size_t)(rowBase + r) * K + kk);
      }
      *(bf16x8*)(Asl + r * LDT + kg) = va;
      *(bf16x8*)(Bsl + r * LDT + kg) = *(const bf16x8*)(W + (size_t)(colBase + r) * K + kk);
    }
    __syncthreads();
    bf16x8 af[4], bfr[4];
#pragma unroll
    for (int mt = 0; mt < 4; ++mt)
      af[mt] = *(const bf16x8*)(Asl + (wm * 64 + mt * 16 + lr) * LDT + lk * 8);
#pragma unroll
    for (int nt = 0; nt < 4; ++nt)
      bfr[nt] = *(const bf16x8*)(Bsl + (wn * 64 + nt * 16 + lr) * LDT + lk * 8);
#pragma unroll
    for (int mt = 0; mt < 4; ++mt)
#pragma unroll
      for (int nt = 0; nt < 4; ++nt) acc[mt][nt] = mfma16(af[mt], bfr[nt], acc[mt][nt]);
    __syncthreads();
  }

#pragma unroll
  for (int mt = 0; mt < 4; ++mt) {
#pragma unroll
    for (int nt = 0; nt < 4; ++nt) {
      const int colG = colBase + wn * 64 + nt * 16 + lr;
      const float bv = bias[colG];
#pragma unroll
      for (int r = 0; r < 4; ++r) {
        const int rowG = rowBase + wm * 64 + mt * 16 + lk * 4 + r;
        const float v = acc[mt][nt][r] + bv;
        if (VAR == 0) {
          outf[(size_t)rowG * N + colG] = v;
        } else if (VAR == 1) {
          outb[(size_t)rowG * N + colG] = f2bf(fmaxf(v, 0.f));
        } else {
          const int b = rowG & 31, t = t0 + (rowG >> 5);
          outf[((size_t)(b * T_FULL + t)) * O_ + colG] = v;
        }
      }
    }
  }
}

// Persistent GRU scan. 56 WGs x 384 threads. WG owns 16 hidden units (3 gate rows each).
// 6 waves = 2 batch-halves x 3 gate strips; one 16x16 MFMA tile per wave, K=896.
// h exchanged via global bf16 hi+lo (double-buffered); fp32 master of own units in LDS.
__global__ __launch_bounds__(384) void scan_gru(
    const float* __restrict__ gates,          // [Tc*32][2688] fp32 (t-major rows)
    const unsigned short* __restrict__ whh,   // [2688][896] bf16
    const float* __restrict__ bhh,            // [2688]
    unsigned short* __restrict__ hhi,         // [2][32][896]
    unsigned short* __restrict__ hlo,         // [2][32][896]
    unsigned short* __restrict__ ornn,        // [Tc*32][896] bf16
    unsigned int* __restrict__ cnt,
    int t0, int Tc) {
  __shared__ float gh[3][32][16];
  __shared__ float hown[32][16];
  const int tid = threadIdx.x;
  const int j0 = blockIdx.x * 16;
  const int lane = tid & 63, wid = tid >> 6;
  const int m = wid & 1, s = wid >> 1;
  const int lr = lane & 15, lk = lane >> 4;

  {  // resume fp32 state for own units (zeroed buffers at t0==0)
    const int rb0 = (t0 + 1) & 1;
    for (int idx = tid; idx < 512; idx += 384) {
      const int b = idx >> 4, c = idx & 15;
      const int o = rb0 * (32 * H_) + b * H_ + j0 + c;
      hown[b][c] = bf2f(hhi[o]) + bf2f(hlo[o]);
    }
  }
  __syncthreads();

  const unsigned short* wp = whh + (size_t)(s * H_ + j0 + lr) * H_ + lk * 8;

  for (int tl = 0; tl < Tc; ++tl) {
    const int t = t0 + tl;
    const int rb = (t + 1) & 1, wb = t & 1;
    const unsigned short* hp = hhi + rb * (32 * H_) + (m * 16 + lr) * H_ + lk * 8;
    const unsigned short* lp = hlo + rb * (32 * H_) + (m * 16 + lr) * H_ + lk * 8;
    f32x4 a0 = {0.f, 0.f, 0.f, 0.f}, a1 = {0.f, 0.f, 0.f, 0.f};
#pragma unroll 4
    for (int kk = 0; kk < 28; ++kk) {
      const bf16x8 bw = *(const bf16x8*)(wp + kk * 32);
      const bf16x8 ah = *(const bf16x8*)(hp + kk * 32);
      const bf16x8 al = *(const bf16x8*)(lp + kk * 32);
      a0 = mfma16(ah, bw, a0);
      a1 = mfma16(al, bw, a1);
    }
#pragma unroll
    for (int r = 0; r < 4; ++r) gh[s][m * 16 + lk * 4 + r][lr] = a0[r] + a1[r];
    __syncthreads();

    for (int idx = tid; idx < 512; idx += 384) {
      const int b = idx >> 4, c = idx & 15;
      const int j = j0 + c;
      const float* gx = gates + ((size_t)tl * 32 + b) * G3_;
      const float xr = gx[j], xz = gx[H_ + j], xn = gx[2 * H_ + j];
      const float ghr = gh[0][b][c] + bhh[j];
      const float ghz = gh[1][b][c] + bhh[H_ + j];
      const float ghn = gh[2][b][c] + bhh[2 * H_ + j];
      const float rr = 1.f / (1.f + __expf(-(xr + ghr)));
      const float zz = 1.f / (1.f + __expf(-(xz + ghz)));
      const float e2 = __expf(2.f * (xn + rr * ghn));
      const float nn = 1.f - 2.f / (e2 + 1.f);
      const float hnew = (1.f - zz) * nn + zz * hown[b][c];
      hown[b][c] = hnew;
      const unsigned short hi = f2bf(hnew);
      const unsigned short lo = f2bf(hnew - bf2f(hi));
      const int o = wb * (32 * H_) + b * H_ + j;
      hhi[o] = hi;
      hlo[o] = lo;
      ornn[((size_t)tl * 32 + b) * H_ + j] = hi;
    }

    // device-scope grid barrier (monotonic counter; zeroed once per launch-call)
    __threadfence();
    __syncthreads();
    if (tid == 0) {
      __hip_atomic_fetch_add(cnt, 1u, __ATOMIC_RELEASE, __HIP_MEMORY_SCOPE_AGENT);
      const unsigned target = (unsigned)(t + 1) * NWG_SCAN;
      while (__hip_atomic_load(cnt, __ATOMIC_RELAXED, __HIP_MEMORY_SCOPE_AGENT) < target)
        __builtin_amdgcn_s_sleep(2);
    }
    __syncthreads();
    __threadfence();
  }
}

extern "C" void kernel_launch(void* const* d_in, const int* in_sizes, int n_in,
                              void* d_out, int out_size, void* d_ws, size_t ws_size,
                              hipStream_t stream) {
  (void)in_sizes; (void)n_in; (void)out_size;
  const int* sample = (const int*)d_in[0];
  const float* icnd = (const float*)d_in[1];
  const float* emb = (const float*)d_in[2];
  const float* wih = (const float*)d_in[3];
  const float* whh = (const float*)d_in[4];
  const float* bih = (const float*)d_in[5];
  const float* bhh = (const float*)d_in[6];
  const float* fc1w = (const float*)d_in[7];
  const float* fc1b = (const float*)d_in[8];
  const float* fc2w = (const float*)d_in[9];
  const float* fc2b = (const float*)d_in[10];
  float* out = (float*)d_out;
  char* ws = (char*)d_ws;

  size_t off = 0;
  auto alloc = [&](size_t bytes) {
    size_t o = off;
    off = (off + bytes + 255) & ~(size_t)255;
    return o;
  };
  const size_t o_cnt = alloc(256);
  const size_t o_hhi = alloc((size_t)2 * 32 * H_ * 2);
  const size_t o_hlo = alloc((size_t)2 * 32 * H_ * 2);
  const size_t zero_end = off;
  const size_t o_emb = alloc((size_t)O_ * EMB_ * 2);
  const size_t o_wih = alloc((size_t)G3_ * XD_ * 2);
  const size_t o_whh = alloc((size_t)G3_ * H_ * 2);
  const size_t o_f1w = alloc((size_t)H_ * H_ * 2);
  const size_t o_f2w = alloc((size_t)O_ * H_ * 2);
  const size_t head = off;

  int Tc = 512;
  while (Tc > 8) {
    size_t need = head + (size_t)Tc * 32 * G3_ * 4 + 2 * ((size_t)Tc * 32 * H_ * 2) + 4096;
    if (need <= ws_size) break;
    Tc >>= 1;
  }
  const size_t o_gat = alloc((size_t)Tc * 32 * G3_ * 4);
  const size_t o_orn = alloc((size_t)Tc * 32 * H_ * 2);
  const size_t o_hid = alloc((size_t)Tc * 32 * H_ * 2);
  (void)o_cnt; (void)o_gat; (void)o_orn; (void)o_hid;

  unsigned short* embb = (unsigned short*)(ws + o_emb);
  unsigned short* wihb = (unsigned short*)(ws + o_wih);
  unsigned short* whhb = (unsigned short*)(ws + o_whh);
  unsigned short* f1wb = (unsigned short*)(ws + o_f1w);
  unsigned short* f2wb = (unsigned short*)(ws + o_f2w);
  float* gat = (float*)(ws + o_gat);
  unsigned short* orn = (unsigned short*)(ws + o_orn);
  unsigned short* hid = (unsigned short*)(ws + o_hid);
  unsigned short* hhi = (unsigned short*)(ws + o_hhi);
  unsigned short* hlo = (unsigned short*)(ws + o_hlo);
  unsigned int* cnt = (unsigned int*)(ws + o_cnt);

  // zero barrier counter + h state (required every call: deterministic replays)
  (void)hipMemsetAsync(ws, 0, zero_end, stream);

  cvt_bf16<<<512, 256, 0, stream>>>(emb, embb, O_ * EMB_);
  cvt_bf16<<<1024, 256, 0, stream>>>(wih, wihb, G3_ * XD_);
  cvt_bf16<<<1024, 256, 0, stream>>>(whh, whhb, G3_ * H_);
  cvt_bf16<<<512, 256, 0, stream>>>(fc1w, f1wb, H_ * H_);
  cvt_bf16<<<512, 256, 0, stream>>>(fc2w, f2wb, O_ * H_);

  const int nch = T_FULL / Tc;
  const int M = Tc * 32;
  for (int c = 0; c < nch; ++c) {
    const int t0 = c * Tc;
    gemm_bf16<0><<<dim3(G3_ / 128, M / 128), 256, 0, stream>>>(
        nullptr, sample, icnd, embb, wihb, bih, gat, nullptr, t0);
    scan_gru<<<NWG_SCAN, 384, 0, stream>>>(gat, whhb, bhh, hhi, hlo, orn, cnt, t0, Tc);
    gemm_bf16<1><<<dim3(H_ / 128, M / 128), 256, 0, stream>>>(
        orn, nullptr, nullptr, nullptr, f1wb, fc1b, nullptr, hid, t0);
    gemm_bf16<2><<<dim3(O_ / 128, M / 128), 256, 0, stream>>>(
        hid, nullptr, nullptr, nullptr, f2wb, fc2b, out, nullptr, t0);
  }
}

// Round 2
// 90033.801 us; speedup vs baseline: 1.4768x; 1.4768x over previous
//
#include <hip/hip_runtime.h>

#define B_ 32
#define T_FULL 4096
#define EMB_ 256
#define XD_ 768
#define H_ 896
#define G3_ 2688
#define O_ 512
#define NWG_SCAN 56

typedef __attribute__((ext_vector_type(8))) short bf16x8;
typedef __attribute__((ext_vector_type(4))) float f32x4;

__device__ __forceinline__ f32x4 mfma16(bf16x8 a, bf16x8 b, f32x4 c) {
  return __builtin_amdgcn_mfma_f32_16x16x32_bf16(a, b, c, 0, 0, 0);
}

__device__ __forceinline__ unsigned short f2bf(float x) {
  union { float f; unsigned u; } v; v.f = x;
  unsigned r = v.u + 0x7fffu + ((v.u >> 16) & 1u);
  return (unsigned short)(r >> 16);
}
__device__ __forceinline__ float bf2f(unsigned short h) {
  union { float f; unsigned u; } v; v.u = ((unsigned)h) << 16;
  return v.f;
}

__device__ __forceinline__ unsigned long long aload64(const unsigned long long* p) {
  return __hip_atomic_load((unsigned long long*)p, __ATOMIC_RELAXED, __HIP_MEMORY_SCOPE_AGENT);
}
__device__ __forceinline__ unsigned aload32(const unsigned* p) {
  return __hip_atomic_load((unsigned*)p, __ATOMIC_RELAXED, __HIP_MEMORY_SCOPE_AGENT);
}
__device__ __forceinline__ void astore32(unsigned* p, unsigned v) {
  __hip_atomic_store(p, v, __ATOMIC_RELAXED, __HIP_MEMORY_SCOPE_AGENT);
}

__global__ __launch_bounds__(256) void cvt_bf16(const float* __restrict__ in,
                                                unsigned short* __restrict__ out, int n) {
  for (int i = blockIdx.x * 256 + threadIdx.x; i < n; i += gridDim.x * 256)
    out[i] = f2bf(in[i]);
}

// VAR: 0 = gates (A = concat(emb[sample], icnd) built on the fly, out fp32 [row][2688])
//      1 = fc1   (A = ornn bf16, out bf16 relu [row][896])
//      2 = fc2   (A = hidden bf16, out fp32 scattered to d_out [b][t][512])
template<int VAR>
__global__ __launch_bounds__(256) void gemm_bf16(
    const unsigned short* __restrict__ A,
    const int* __restrict__ sample,
    const float* __restrict__ icnd,
    const unsigned short* __restrict__ embb,
    const unsigned short* __restrict__ W,
    const float* __restrict__ bias,
    float* __restrict__ outf,
    unsigned short* __restrict__ outb,
    int t0) {
  constexpr int K = (VAR == 0) ? XD_ : H_;
  constexpr int N = (VAR == 0) ? G3_ : (VAR == 1 ? H_ : O_);
  constexpr int LDT = 48;
  __shared__ __align__(16) unsigned short Asl[128 * LDT];
  __shared__ __align__(16) unsigned short Bsl[128 * LDT];
  const int tid = threadIdx.x;
  const int rowBase = blockIdx.y * 128, colBase = blockIdx.x * 128;
  const int lane = tid & 63, wid = tid >> 6;
  const int wm = wid >> 1, wn = wid & 1;
  const int lr = lane & 15, lk = lane >> 4;
  const f32x4 fzero = {0.f, 0.f, 0.f, 0.f};
  f32x4 acc[4][4];
#pragma unroll
  for (int i = 0; i < 4; ++i)
#pragma unroll
    for (int j = 0; j < 4; ++j) acc[i][j] = fzero;

  for (int k0 = 0; k0 < K; k0 += 32) {
#pragma unroll
    for (int s = 0; s < 2; ++s) {
      const int seg = tid + s * 256;           // 512 segments of 8 elems
      const int r = seg >> 2, kg = (seg & 3) * 8;
      const int kk = k0 + kg;
      bf16x8 va;
      if (VAR == 0) {
        const int rowG = rowBase + r;
        const int b = rowG & 31, t = t0 + (rowG >> 5);
        if (kk < EMB_) {
          const int e = sample[b * T_FULL + t];
          va = *(const bf16x8*)(embb + e * EMB_ + kk);
        } else {
          const float* p = icnd + ((size_t)(b * T_FULL + t)) * 512 + (kk - EMB_);
          const float4 f0 = *(const float4*)p;
          const float4 f1 = *(const float4*)(p + 4);
          va[0] = (short)f2bf(f0.x); va[1] = (short)f2bf(f0.y);
          va[2] = (short)f2bf(f0.z); va[3] = (short)f2bf(f0.w);
          va[4] = (short)f2bf(f1.x); va[5] = (short)f2bf(f1.y);
          va[6] = (short)f2bf(f1.z); va[7] = (short)f2bf(f1.w);
        }
      } else {
        va = *(const bf16x8*)(A + (size_t)(rowBase + r) * K + kk);
      }
      *(bf16x8*)(Asl + r * LDT + kg) = va;
      *(bf16x8*)(Bsl + r * LDT + kg) = *(const bf16x8*)(W + (size_t)(colBase + r) * K + kk);
    }
    __syncthreads();
    bf16x8 af[4], bfr[4];
#pragma unroll
    for (int mt = 0; mt < 4; ++mt)
      af[mt] = *(const bf16x8*)(Asl + (wm * 64 + mt * 16 + lr) * LDT + lk * 8);
#pragma unroll
    for (int nt = 0; nt < 4; ++nt)
      bfr[nt] = *(const bf16x8*)(Bsl + (wn * 64 + nt * 16 + lr) * LDT + lk * 8);
#pragma unroll
    for (int mt = 0; mt < 4; ++mt)
#pragma unroll
      for (int nt = 0; nt < 4; ++nt) acc[mt][nt] = mfma16(af[mt], bfr[nt], acc[mt][nt]);
    __syncthreads();
  }

#pragma unroll
  for (int mt = 0; mt < 4; ++mt) {
#pragma unroll
    for (int nt = 0; nt < 4; ++nt) {
      const int colG = colBase + wn * 64 + nt * 16 + lr;
      const float bv = bias[colG];
#pragma unroll
      for (int r = 0; r < 4; ++r) {
        const int rowG = rowBase + wm * 64 + mt * 16 + lk * 4 + r;
        const float v = acc[mt][nt][r] + bv;
        if (VAR == 0) {
          outf[(size_t)rowG * N + colG] = v;
        } else if (VAR == 1) {
          outb[(size_t)rowG * N + colG] = f2bf(fmaxf(v, 0.f));
        } else {
          const int b = rowG & 31, t = t0 + (rowG >> 5);
          outf[((size_t)(b * T_FULL + t)) * O_ + colG] = v;
        }
      }
    }
  }
}

// Persistent GRU scan, v2: fence-free.
// - h exchanged via AGENT-scope relaxed atomics (sc0 sc1 -> bypass L1/L2, served by
//   coherent L3). Weights/gates use plain cached loads and stay hot in L1/L2 forever.
// - grid barrier = per-WG arrival slot (relaxed store) + wave0 lane-parallel poll.
//   No __threadfence anywhere -> no per-step L2 writeback/invalidate.
__global__ __launch_bounds__(384) void scan_gru(
    const float* __restrict__ gates,          // [Tc*32][2688] fp32 (t-major rows)
    const unsigned short* __restrict__ whh,   // [2688][896] bf16
    const float* __restrict__ bhh,            // [2688]
    unsigned short* __restrict__ hhi,         // [2][32][896] bf16 (hi part)
    unsigned short* __restrict__ hlo,         // [2][32][896] bf16 (lo part)
    unsigned short* __restrict__ ornn,        // [Tc*32][896] bf16
    unsigned int* __restrict__ arr,           // [64] arrival slots (zeroed per call)
    int t0, int Tc) {
  __shared__ float gh[3][32][16];
  __shared__ float hown[32][16];
  const int tid = threadIdx.x;
  const int j0 = blockIdx.x * 16;
  const int lane = tid & 63, wid = tid >> 6;
  const int m = wid & 1, s = wid >> 1;
  const int lr = lane & 15, lk = lane >> 4;

  {  // resume fp32 state for own units (buffers zeroed by host memset at t0==0)
    const int rb0 = (t0 + 1) & 1;
    if (tid < 256) {
      const int b = tid >> 3, c2 = (tid & 7) * 2;
      const int o = rb0 * (32 * H_) + b * H_ + j0 + c2;
      const unsigned hi01 = aload32((const unsigned*)(hhi + o));
      const unsigned lo01 = aload32((const unsigned*)(hlo + o));
      hown[b][c2]     = bf2f((unsigned short)(hi01 & 0xffff)) + bf2f((unsigned short)(lo01 & 0xffff));
      hown[b][c2 + 1] = bf2f((unsigned short)(hi01 >> 16))    + bf2f((unsigned short)(lo01 >> 16));
    }
  }
  __syncthreads();

  const unsigned short* wp = whh + (size_t)(s * H_ + j0 + lr) * H_ + lk * 8;
  const int rowm = m * 16 + lr;
  const f32x4 fzero = {0.f, 0.f, 0.f, 0.f};

  for (int tl = 0; tl < Tc; ++tl) {
    const int t = t0 + tl;
    const int rb = (t + 1) & 1, wb = t & 1;
    const unsigned long long* hq =
        (const unsigned long long*)(hhi + rb * (32 * H_) + rowm * H_) + lk * 2;
    const unsigned long long* lq =
        (const unsigned long long*)(hlo + rb * (32 * H_) + rowm * H_) + lk * 2;
    f32x4 a0 = fzero, a1 = fzero;
#pragma unroll
    for (int kk = 0; kk < 28; ++kk) {
      union { bf16x8 v; unsigned long long q[2]; } ah, al;
      ah.q[0] = aload64(hq + kk * 8);
      ah.q[1] = aload64(hq + kk * 8 + 1);
      al.q[0] = aload64(lq + kk * 8);
      al.q[1] = aload64(lq + kk * 8 + 1);
      const bf16x8 bw = *(const bf16x8*)(wp + kk * 32);
      a0 = mfma16(ah.v, bw, a0);
      a1 = mfma16(al.v, bw, a1);
    }
#pragma unroll
    for (int r = 0; r < 4; ++r) gh[s][m * 16 + lk * 4 + r][lr] = a0[r] + a1[r];
    __syncthreads();

    if (tid < 256) {
      const int b = tid >> 3, c2 = (tid & 7) * 2;
      const int j = j0 + c2;
      const float* gx = gates + ((size_t)tl * 32 + b) * G3_;
      const float2 xr = *(const float2*)(gx + j);
      const float2 xz = *(const float2*)(gx + H_ + j);
      const float2 xn = *(const float2*)(gx + 2 * H_ + j);
      float hn2[2];
#pragma unroll
      for (int e = 0; e < 2; ++e) {
        const float ghr = gh[0][b][c2 + e] + bhh[j + e];
        const float ghz = gh[1][b][c2 + e] + bhh[H_ + j + e];
        const float ghn = gh[2][b][c2 + e] + bhh[2 * H_ + j + e];
        const float xrv = e ? xr.y : xr.x;
        const float xzv = e ? xz.y : xz.x;
        const float xnv = e ? xn.y : xn.x;
        const float rr = 1.f / (1.f + __expf(-(xrv + ghr)));
        const float zz = 1.f / (1.f + __expf(-(xzv + ghz)));
        const float e2 = __expf(2.f * (xnv + rr * ghn));
        const float nn = 1.f - 2.f / (e2 + 1.f);
        const float hnew = (1.f - zz) * nn + zz * hown[b][c2 + e];
        hown[b][c2 + e] = hnew;
        hn2[e] = hnew;
      }
      const unsigned short h0 = f2bf(hn2[0]), h1 = f2bf(hn2[1]);
      const unsigned short l0 = f2bf(hn2[0] - bf2f(h0)), l1 = f2bf(hn2[1] - bf2f(h1));
      const unsigned hi01 = (unsigned)h0 | ((unsigned)h1 << 16);
      const unsigned lo01 = (unsigned)l0 | ((unsigned)l1 << 16);
      const int o = wb * (32 * H_) + b * H_ + j;
      astore32((unsigned*)(hhi + o), hi01);
      astore32((unsigned*)(hlo + o), lo01);
      *(unsigned*)(ornn + ((size_t)tl * 32 + b) * H_ + j) = hi01;
    }

    // fence-free grid barrier: drain own sc1 stores to the coherence point,
    // then arrival-slot store + lane-parallel poll of all 56 slots.
    asm volatile("s_waitcnt vmcnt(0)" ::: "memory");
    __syncthreads();
    if (wid == 0) {
      const unsigned tgt = (unsigned)(t + 1);
      if (lane == 0) astore32(arr + blockIdx.x, tgt);
      for (;;) {
        const unsigned v = (lane < NWG_SCAN) ? aload32(arr + lane) : tgt;
        if (__all(v >= tgt)) break;
        __builtin_amdgcn_s_sleep(2);
      }
    }
    __syncthreads();
  }
}

extern "C" void kernel_launch(void* const* d_in, const int* in_sizes, int n_in,
                              void* d_out, int out_size, void* d_ws, size_t ws_size,
                              hipStream_t stream) {
  (void)in_sizes; (void)n_in; (void)out_size;
  const int* sample = (const int*)d_in[0];
  const float* icnd = (const float*)d_in[1];
  const float* emb = (const float*)d_in[2];
  const float* wih = (const float*)d_in[3];
  const float* whh = (const float*)d_in[4];
  const float* bih = (const float*)d_in[5];
  const float* bhh = (const float*)d_in[6];
  const float* fc1w = (const float*)d_in[7];
  const float* fc1b = (const float*)d_in[8];
  const float* fc2w = (const float*)d_in[9];
  const float* fc2b = (const float*)d_in[10];
  float* out = (float*)d_out;
  char* ws = (char*)d_ws;

  size_t off = 0;
  auto alloc = [&](size_t bytes) {
    size_t o = off;
    off = (off + bytes + 255) & ~(size_t)255;
    return o;
  };
  const size_t o_arr = alloc(256);
  const size_t o_hhi = alloc((size_t)2 * 32 * H_ * 2);
  const size_t o_hlo = alloc((size_t)2 * 32 * H_ * 2);
  const size_t zero_end = off;
  const size_t o_emb = alloc((size_t)O_ * EMB_ * 2);
  const size_t o_wih = alloc((size_t)G3_ * XD_ * 2);
  const size_t o_whh = alloc((size_t)G3_ * H_ * 2);
  const size_t o_f1w = alloc((size_t)H_ * H_ * 2);
  const size_t o_f2w = alloc((size_t)O_ * H_ * 2);
  const size_t head = off;

  int Tc = 512;
  while (Tc > 8) {
    size_t need = head + (size_t)Tc * 32 * G3_ * 4 + 2 * ((size_t)Tc * 32 * H_ * 2) + 4096;
    if (need <= ws_size) break;
    Tc >>= 1;
  }
  const size_t o_gat = alloc((size_t)Tc * 32 * G3_ * 4);
  const size_t o_orn = alloc((size_t)Tc * 32 * H_ * 2);
  const size_t o_hid = alloc((size_t)Tc * 32 * H_ * 2);
  (void)o_gat; (void)o_orn; (void)o_hid;

  unsigned short* embb = (unsigned short*)(ws + o_emb);
  unsigned short* wihb = (unsigned short*)(ws + o_wih);
  unsigned short* whhb = (unsigned short*)(ws + o_whh);
  unsigned short* f1wb = (unsigned short*)(ws + o_f1w);
  unsigned short* f2wb = (unsigned short*)(ws + o_f2w);
  float* gat = (float*)(ws + o_gat);
  unsigned short* orn = (unsigned short*)(ws + o_orn);
  unsigned short* hid = (unsigned short*)(ws + o_hid);
  unsigned short* hhi = (unsigned short*)(ws + o_hhi);
  unsigned short* hlo = (unsigned short*)(ws + o_hlo);
  unsigned int* arr = (unsigned int*)(ws + o_arr);

  // zero arrival slots + h state (required every call: deterministic replays)
  (void)hipMemsetAsync(ws, 0, zero_end, stream);

  cvt_bf16<<<512, 256, 0, stream>>>(emb, embb, O_ * EMB_);
  cvt_bf16<<<1024, 256, 0, stream>>>(wih, wihb, G3_ * XD_);
  cvt_bf16<<<1024, 256, 0, stream>>>(whh, whhb, G3_ * H_);
  cvt_bf16<<<512, 256, 0, stream>>>(fc1w, f1wb, H_ * H_);
  cvt_bf16<<<512, 256, 0, stream>>>(fc2w, f2wb, O_ * H_);

  const int nch = T_FULL / Tc;
  const int M = Tc * 32;
  for (int c = 0; c < nch; ++c) {
    const int t0 = c * Tc;
    gemm_bf16<0><<<dim3(G3_ / 128, M / 128), 256, 0, stream>>>(
        nullptr, sample, icnd, embb, wihb, bih, gat, nullptr, t0);
    scan_gru<<<NWG_SCAN, 384, 0, stream>>>(gat, whhb, bhh, hhi, hlo, orn, arr, t0, Tc);
    gemm_bf16<1><<<dim3(H_ / 128, M / 128), 256, 0, stream>>>(
        orn, nullptr, nullptr, nullptr, f1wb, fc1b, nullptr, hid, t0);
    gemm_bf16<2><<<dim3(O_ / 128, M / 128), 256, 0, stream>>>(
        hid, nullptr, nullptr, nullptr, f2wb, fc2b, out, nullptr, t0);
  }
}

// Round 3
// 39138.370 us; speedup vs baseline: 3.3973x; 2.3004x over previous
//
#include <hip/hip_runtime.h>

#define B_ 32
#define T_FULL 4096
#define EMB_ 256
#define XD_ 768
#define H_ 896
#define G3_ 2688
#define O_ 512
#define NWG_SCAN 28
#define UJ 32
#define THR_SCAN 768

typedef __attribute__((ext_vector_type(8))) short bf16x8;
typedef __attribute__((ext_vector_type(4))) float f32x4;

__device__ __forceinline__ f32x4 mfma16(bf16x8 a, bf16x8 b, f32x4 c) {
  return __builtin_amdgcn_mfma_f32_16x16x32_bf16(a, b, c, 0, 0, 0);
}

__device__ __forceinline__ unsigned short f2bf(float x) {
  union { float f; unsigned u; } v; v.f = x;
  unsigned r = v.u + 0x7fffu + ((v.u >> 16) & 1u);
  return (unsigned short)(r >> 16);
}
__device__ __forceinline__ float bf2f(unsigned short h) {
  union { float f; unsigned u; } v; v.u = ((unsigned)h) << 16;
  return v.f;
}

__device__ __forceinline__ unsigned long long aload64(const unsigned long long* p) {
  return __hip_atomic_load((unsigned long long*)p, __ATOMIC_RELAXED, __HIP_MEMORY_SCOPE_AGENT);
}
__device__ __forceinline__ unsigned aload32(const unsigned* p) {
  return __hip_atomic_load((unsigned*)p, __ATOMIC_RELAXED, __HIP_MEMORY_SCOPE_AGENT);
}
__device__ __forceinline__ void astore32(unsigned* p, unsigned v) {
  __hip_atomic_store(p, v, __ATOMIC_RELAXED, __HIP_MEMORY_SCOPE_AGENT);
}

__global__ __launch_bounds__(256) void cvt_bf16(const float* __restrict__ in,
                                                unsigned short* __restrict__ out, int n) {
  for (int i = blockIdx.x * 256 + threadIdx.x; i < n; i += gridDim.x * 256)
    out[i] = f2bf(in[i]);
}

// VAR: 0 = gates (A = concat(emb[sample], icnd) built on the fly, out fp32 [row][2688])
//      1 = fc1   (A = ornn bf16, out bf16 relu [row][896])
//      2 = fc2   (A = hidden bf16, out fp32 scattered to d_out [b][t][512])
template<int VAR>
__global__ __launch_bounds__(256) void gemm_bf16(
    const unsigned short* __restrict__ A,
    const int* __restrict__ sample,
    const float* __restrict__ icnd,
    const unsigned short* __restrict__ embb,
    const unsigned short* __restrict__ W,
    const float* __restrict__ bias,
    float* __restrict__ outf,
    unsigned short* __restrict__ outb,
    int t0) {
  constexpr int K = (VAR == 0) ? XD_ : H_;
  constexpr int N = (VAR == 0) ? G3_ : (VAR == 1 ? H_ : O_);
  constexpr int LDT = 48;
  __shared__ __align__(16) unsigned short Asl[128 * LDT];
  __shared__ __align__(16) unsigned short Bsl[128 * LDT];
  const int tid = threadIdx.x;
  const int rowBase = blockIdx.y * 128, colBase = blockIdx.x * 128;
  const int lane = tid & 63, wid = tid >> 6;
  const int wm = wid >> 1, wn = wid & 1;
  const int lr = lane & 15, lk = lane >> 4;
  const f32x4 fzero = {0.f, 0.f, 0.f, 0.f};
  f32x4 acc[4][4];
#pragma unroll
  for (int i = 0; i < 4; ++i)
#pragma unroll
    for (int j = 0; j < 4; ++j) acc[i][j] = fzero;

  for (int k0 = 0; k0 < K; k0 += 32) {
#pragma unroll
    for (int s = 0; s < 2; ++s) {
      const int seg = tid + s * 256;           // 512 segments of 8 elems
      const int r = seg >> 2, kg = (seg & 3) * 8;
      const int kk = k0 + kg;
      bf16x8 va;
      if (VAR == 0) {
        const int rowG = rowBase + r;
        const int b = rowG & 31, t = t0 + (rowG >> 5);
        if (kk < EMB_) {
          const int e = sample[b * T_FULL + t];
          va = *(const bf16x8*)(embb + e * EMB_ + kk);
        } else {
          const float* p = icnd + ((size_t)(b * T_FULL + t)) * 512 + (kk - EMB_);
          const float4 f0 = *(const float4*)p;
          const float4 f1 = *(const float4*)(p + 4);
          va[0] = (short)f2bf(f0.x); va[1] = (short)f2bf(f0.y);
          va[2] = (short)f2bf(f0.z); va[3] = (short)f2bf(f0.w);
          va[4] = (short)f2bf(f1.x); va[5] = (short)f2bf(f1.y);
          va[6] = (short)f2bf(f1.z); va[7] = (short)f2bf(f1.w);
        }
      } else {
        va = *(const bf16x8*)(A + (size_t)(rowBase + r) * K + kk);
      }
      *(bf16x8*)(Asl + r * LDT + kg) = va;
      *(bf16x8*)(Bsl + r * LDT + kg) = *(const bf16x8*)(W + (size_t)(colBase + r) * K + kk);
    }
    __syncthreads();
    bf16x8 af[4], bfr[4];
#pragma unroll
    for (int mt = 0; mt < 4; ++mt)
      af[mt] = *(const bf16x8*)(Asl + (wm * 64 + mt * 16 + lr) * LDT + lk * 8);
#pragma unroll
    for (int nt = 0; nt < 4; ++nt)
      bfr[nt] = *(const bf16x8*)(Bsl + (wn * 64 + nt * 16 + lr) * LDT + lk * 8);
#pragma unroll
    for (int mt = 0; mt < 4; ++mt)
#pragma unroll
      for (int nt = 0; nt < 4; ++nt) acc[mt][nt] = mfma16(af[mt], bfr[nt], acc[mt][nt]);
    __syncthreads();
  }

#pragma unroll
  for (int mt = 0; mt < 4; ++mt) {
#pragma unroll
    for (int nt = 0; nt < 4; ++nt) {
      const int colG = colBase + wn * 64 + nt * 16 + lr;
      const float bv = bias[colG];
#pragma unroll
      for (int r = 0; r < 4; ++r) {
        const int rowG = rowBase + wm * 64 + mt * 16 + lk * 4 + r;
        const float v = acc[mt][nt][r] + bv;
        if (VAR == 0) {
          outf[(size_t)rowG * N + colG] = v;
        } else if (VAR == 1) {
          outb[(size_t)rowG * N + colG] = f2bf(fmaxf(v, 0.f));
        } else {
          const int b = rowG & 31, t = t0 + (rowG >> 5);
          outf[((size_t)(b * T_FULL + t)) * O_ + colG] = v;
        }
      }
    }
  }
}

// Persistent GRU scan v3: latency-parallel step pipeline.
// 28 WGs x 768 threads (12 waves = 3 gate-strips x 2 batch-halves x 2 col-tiles),
// 32 hidden units per WG. Per step:
//   1. prefetch gates (plain cached loads -> regs, consumed ~3us later)
//   2. cooperative flat gather of h hi+lo (coalesced atomic u64) -> swizzled LDS
//   3. MFMA from LDS (conflict-free ds_read_b128), W streamed from L1/L2
//   4. elementwise in regs; h stores via agent atomics; drain; arrival+poll barrier
__global__ __launch_bounds__(THR_SCAN) void scan_gru(
    const float* __restrict__ gates,          // [Tc*32][2688] fp32 (t-major rows)
    const unsigned short* __restrict__ whh,   // [2688][896] bf16
    const float* __restrict__ bhh,            // [2688]
    unsigned short* __restrict__ hhi,         // [2][32][896] bf16 (hi part)
    unsigned short* __restrict__ hlo,         // [2][32][896] bf16 (lo part)
    unsigned short* __restrict__ ornn,        // [Tc*32][896] bf16
    unsigned int* __restrict__ arr,           // arrival slots (zeroed per call)
    int t0, int Tc) {
  __shared__ __align__(16) unsigned short hst[2][32 * H_];  // 114688 B, swizzled
  __shared__ float gh[3][32][UJ + 1];                       // padded vs bank conflict
  const int tid = threadIdx.x;
  const int j0 = blockIdx.x * UJ;
  const int lane = tid & 63, wid = tid >> 6;
  const int m = wid & 1;            // batch half
  const int s = (wid >> 1) % 3;     // gate strip
  const int cn = wid / 6;           // col tile within UJ
  const int lr = lane & 15, lk = lane >> 4;
  char* hbase = (char*)&hst[0][0];

  // per-thread elementwise identity (tid<512): 2 units of one batch row
  const int eb = tid >> 4, ec = (tid & 15) * 2;
  float hown0 = 0.f, hown1 = 0.f;
  float bh_r0 = 0.f, bh_r1 = 0.f, bh_z0 = 0.f, bh_z1 = 0.f, bh_n0 = 0.f, bh_n1 = 0.f;
  if (tid < 512) {
    const int j = j0 + ec;
    bh_r0 = bhh[j];          bh_r1 = bhh[j + 1];
    bh_z0 = bhh[H_ + j];     bh_z1 = bhh[H_ + j + 1];
    bh_n0 = bhh[2 * H_ + j]; bh_n1 = bhh[2 * H_ + j + 1];
    const int rb0 = (t0 + 1) & 1;
    const int o = rb0 * (32 * H_) + eb * H_ + j;
    const unsigned hi01 = aload32((const unsigned*)(hhi + o));
    const unsigned lo01 = aload32((const unsigned*)(hlo + o));
    hown0 = bf2f((unsigned short)(hi01 & 0xffff)) + bf2f((unsigned short)(lo01 & 0xffff));
    hown1 = bf2f((unsigned short)(hi01 >> 16)) + bf2f((unsigned short)(lo01 >> 16));
  }

  const unsigned short* wp = whh + (size_t)(s * H_ + j0 + cn * 16 + lr) * H_ + lk * 8;
  const int rrow = m * 16 + lr;
  const int rowb = rrow * 1792;
  const int sw_r = (rrow & 7) << 4;
  const f32x4 fzero = {0.f, 0.f, 0.f, 0.f};

  for (int tl = 0; tl < Tc; ++tl) {
    const int t = t0 + tl;
    const int rb = (t + 1) & 1, wb = t & 1;

    // 1. gates prefetch into registers (plain cached; consumed after MFMA phase)
    float2 pxr = {0.f, 0.f}, pxz = {0.f, 0.f}, pxn = {0.f, 0.f};
    if (tid < 512) {
      const float* gx = gates + ((size_t)tl * 32 + eb) * G3_;
      pxr = *(const float2*)(gx + j0 + ec);
      pxz = *(const float2*)(gx + H_ + j0 + ec);
      pxn = *(const float2*)(gx + 2 * H_ + j0 + ec);
    }

    // 2. cooperative h gather -> swizzled LDS (coalesced, all-parallel atomics)
    {
      const unsigned long long* sh = (const unsigned long long*)(hhi + rb * (32 * H_));
      const unsigned long long* sl = (const unsigned long long*)(hlo + rb * (32 * H_));
#pragma unroll
      for (int k = 0; k < 10; ++k) {
        const int i = tid + k * THR_SCAN;      // u64 index within a 7168-u64 plane
        if (i < 7168) {
          const unsigned long long vh = aload64(sh + i);
          const unsigned long long vl = aload64(sl + i);
          const int row = i / 224;             // 224 u64 per 896-elem row
          const int cb = (i - row * 224) * 8;  // byte col
          const int dst = row * 1792 + (cb ^ ((row & 7) << 4));
          *(unsigned long long*)(hbase + dst) = vh;
          *(unsigned long long*)(hbase + 57344 + dst) = vl;
        }
      }
    }
    __syncthreads();

    // 3. MFMA from LDS; W streamed from cache
    f32x4 a0 = fzero, a1 = fzero;
#pragma unroll
    for (int kk = 0; kk < 28; ++kk) {
      const int off = (lk * 16 + kk * 64) ^ sw_r;
      const bf16x8 ah = *(const bf16x8*)(hbase + rowb + off);
      const bf16x8 al = *(const bf16x8*)(hbase + 57344 + rowb + off);
      const bf16x8 bw = *(const bf16x8*)(wp + kk * 32);
      a0 = mfma16(ah, bw, a0);
      a1 = mfma16(al, bw, a1);
    }
#pragma unroll
    for (int r = 0; r < 4; ++r) gh[s][m * 16 + lk * 4 + r][cn * 16 + lr] = a0[r] + a1[r];
    __syncthreads();

    // 4. elementwise GRU cell + h exchange stores
    if (tid < 512) {
      const float ghr0 = gh[0][eb][ec] + bh_r0, ghr1 = gh[0][eb][ec + 1] + bh_r1;
      const float ghz0 = gh[1][eb][ec] + bh_z0, ghz1 = gh[1][eb][ec + 1] + bh_z1;
      const float ghn0 = gh[2][eb][ec] + bh_n0, ghn1 = gh[2][eb][ec + 1] + bh_n1;
      const float r0 = 1.f / (1.f + __expf(-(pxr.x + ghr0)));
      const float r1 = 1.f / (1.f + __expf(-(pxr.y + ghr1)));
      const float z0 = 1.f / (1.f + __expf(-(pxz.x + ghz0)));
      const float z1 = 1.f / (1.f + __expf(-(pxz.y + ghz1)));
      const float e0 = __expf(2.f * (pxn.x + r0 * ghn0));
      const float e1 = __expf(2.f * (pxn.y + r1 * ghn1));
      const float n0 = 1.f - 2.f / (e0 + 1.f);
      const float n1 = 1.f - 2.f / (e1 + 1.f);
      hown0 = (1.f - z0) * n0 + z0 * hown0;
      hown1 = (1.f - z1) * n1 + z1 * hown1;
      const unsigned short h0 = f2bf(hown0), h1 = f2bf(hown1);
      const unsigned short l0 = f2bf(hown0 - bf2f(h0)), l1 = f2bf(hown1 - bf2f(h1));
      const unsigned hi01 = (unsigned)h0 | ((unsigned)h1 << 16);
      const unsigned lo01 = (unsigned)l0 | ((unsigned)l1 << 16);
      const int o = wb * (32 * H_) + eb * H_ + j0 + ec;
      astore32((unsigned*)(hhi + o), hi01);
      astore32((unsigned*)(hlo + o), lo01);
      *(unsigned*)(ornn + ((size_t)tl * 32 + eb) * H_ + j0 + ec) = hi01;
    }

    // drain h stores to coherence point, then arrival + lane-parallel poll
    asm volatile("s_waitcnt vmcnt(0)" ::: "memory");
    __syncthreads();
    if (wid == 0) {
      const unsigned tgt = (unsigned)(t + 1);
      if (lane == 0) astore32(arr + blockIdx.x, tgt);
      for (;;) {
        const unsigned v = (lane < NWG_SCAN) ? aload32(arr + lane) : tgt;
        if (__all(v >= tgt)) break;
        __builtin_amdgcn_s_sleep(1);
      }
    }
    __syncthreads();
  }
}

extern "C" void kernel_launch(void* const* d_in, const int* in_sizes, int n_in,
                              void* d_out, int out_size, void* d_ws, size_t ws_size,
                              hipStream_t stream) {
  (void)in_sizes; (void)n_in; (void)out_size;
  const int* sample = (const int*)d_in[0];
  const float* icnd = (const float*)d_in[1];
  const float* emb = (const float*)d_in[2];
  const float* wih = (const float*)d_in[3];
  const float* whh = (const float*)d_in[4];
  const float* bih = (const float*)d_in[5];
  const float* bhh = (const float*)d_in[6];
  const float* fc1w = (const float*)d_in[7];
  const float* fc1b = (const float*)d_in[8];
  const float* fc2w = (const float*)d_in[9];
  const float* fc2b = (const float*)d_in[10];
  float* out = (float*)d_out;
  char* ws = (char*)d_ws;

  size_t off = 0;
  auto alloc = [&](size_t bytes) {
    size_t o = off;
    off = (off + bytes + 255) & ~(size_t)255;
    return o;
  };
  const size_t o_arr = alloc(256);
  const size_t o_hhi = alloc((size_t)2 * 32 * H_ * 2);
  const size_t o_hlo = alloc((size_t)2 * 32 * H_ * 2);
  const size_t zero_end = off;
  const size_t o_emb = alloc((size_t)O_ * EMB_ * 2);
  const size_t o_wih = alloc((size_t)G3_ * XD_ * 2);
  const size_t o_whh = alloc((size_t)G3_ * H_ * 2);
  const size_t o_f1w = alloc((size_t)H_ * H_ * 2);
  const size_t o_f2w = alloc((size_t)O_ * H_ * 2);
  const size_t head = off;

  int Tc = 512;
  while (Tc > 8) {
    size_t need = head + (size_t)Tc * 32 * G3_ * 4 + 2 * ((size_t)Tc * 32 * H_ * 2) + 4096;
    if (need <= ws_size) break;
    Tc >>= 1;
  }
  const size_t o_gat = alloc((size_t)Tc * 32 * G3_ * 4);
  const size_t o_orn = alloc((size_t)Tc * 32 * H_ * 2);
  const size_t o_hid = alloc((size_t)Tc * 32 * H_ * 2);
  (void)o_gat; (void)o_orn; (void)o_hid;

  unsigned short* embb = (unsigned short*)(ws + o_emb);
  unsigned short* wihb = (unsigned short*)(ws + o_wih);
  unsigned short* whhb = (unsigned short*)(ws + o_whh);
  unsigned short* f1wb = (unsigned short*)(ws + o_f1w);
  unsigned short* f2wb = (unsigned short*)(ws + o_f2w);
  float* gat = (float*)(ws + o_gat);
  unsigned short* orn = (unsigned short*)(ws + o_orn);
  unsigned short* hid = (unsigned short*)(ws + o_hid);
  unsigned short* hhi = (unsigned short*)(ws + o_hhi);
  unsigned short* hlo = (unsigned short*)(ws + o_hlo);
  unsigned int* arr = (unsigned int*)(ws + o_arr);

  // zero arrival slots + h state (required every call: deterministic replays)
  (void)hipMemsetAsync(ws, 0, zero_end, stream);

  cvt_bf16<<<512, 256, 0, stream>>>(emb, embb, O_ * EMB_);
  cvt_bf16<<<1024, 256, 0, stream>>>(wih, wihb, G3_ * XD_);
  cvt_bf16<<<1024, 256, 0, stream>>>(whh, whhb, G3_ * H_);
  cvt_bf16<<<512, 256, 0, stream>>>(fc1w, f1wb, H_ * H_);
  cvt_bf16<<<512, 256, 0, stream>>>(fc2w, f2wb, O_ * H_);

  const int nch = T_FULL / Tc;
  const int M = Tc * 32;
  for (int c = 0; c < nch; ++c) {
    const int t0 = c * Tc;
    gemm_bf16<0><<<dim3(G3_ / 128, M / 128), 256, 0, stream>>>(
        nullptr, sample, icnd, embb, wihb, bih, gat, nullptr, t0);
    scan_gru<<<NWG_SCAN, THR_SCAN, 0, stream>>>(gat, whhb, bhh, hhi, hlo, orn, arr, t0, Tc);
    gemm_bf16<1><<<dim3(H_ / 128, M / 128), 256, 0, stream>>>(
        orn, nullptr, nullptr, nullptr, f1wb, fc1b, nullptr, hid, t0);
    gemm_bf16<2><<<dim3(O_ / 128, M / 128), 256, 0, stream>>>(
        hid, nullptr, nullptr, nullptr, f2wb, fc2b, out, nullptr, t0);
  }
}